// Round 6
// baseline (833.091 us; speedup 1.0000x reference)
//
#include <hip/hip_runtime.h>
#include <hip/hip_bf16.h>
#include <math.h>

#define H_ 16
#define LQ_ 2048
#define LK_ 2048
#define D_ 64
#define QB_ 16                  // q rows per block
#define NWAVE_ 16               // 1024 threads
#define COLSW_ 128              // k-cols per wave (k-split)
#define NT_ 8                   // 16-col tiles per wave

using bf16x8  = __attribute__((ext_vector_type(8))) short;
using short4v = __attribute__((ext_vector_type(4))) short;
using floatx4 = __attribute__((ext_vector_type(4))) float;

__device__ __forceinline__ unsigned short f2bf(float x) {
  unsigned u = __builtin_bit_cast(unsigned, x);
  return (unsigned short)((u + 0x7fffu + ((u >> 16) & 1u)) >> 16);
}
__device__ __forceinline__ float bf2f(unsigned short b) {
  return __builtin_bit_cast(float, ((unsigned)b) << 16);
}
__device__ __forceinline__ void hilo8(const float* __restrict__ x, bf16x8& hv, bf16x8& lv) {
#pragma unroll
  for (int j = 0; j < 8; ++j) {
    unsigned short hb = f2bf(x[j]);
    float d = x[j] - bf2f(hb);
    hv[j] = (short)hb;
    lv[j] = (short)(unsigned short)(__builtin_bit_cast(unsigned, d) >> 16);
  }
}
__device__ __forceinline__ void hilo4(const float* __restrict__ x, short4v& hv, short4v& lv) {
#pragma unroll
  for (int j = 0; j < 4; ++j) {
    unsigned short hb = f2bf(x[j]);
    float d = x[j] - bf2f(hb);
    hv[j] = (short)hb;
    lv[j] = (short)(unsigned short)(__builtin_bit_cast(unsigned, d) >> 16);
  }
}

__device__ __forceinline__ floatx4 mfma32(bf16x8 a, bf16x8 b, floatx4 c) {
  return __builtin_amdgcn_mfma_f32_16x16x32_bf16(a, b, c, 0, 0, 0);
}
__device__ __forceinline__ floatx4 mfma16(short4v a, short4v b, floatx4 c) {
#if __has_builtin(__builtin_amdgcn_mfma_f32_16x16x16bf16_1k)
  return __builtin_amdgcn_mfma_f32_16x16x16bf16_1k(a, b, c, 0, 0, 0);
#else
  floatx4 d;
  asm("v_mfma_f32_16x16x16_bf16 %0, %1, %2, %3" : "=&v"(d) : "v"(a), "v"(b), "v"(c));
  return d;
#endif
}

// ---- mask dtype detect: int32 0/1 words never have nonzero high bytes ----
__global__ void detect_mask_kernel(const unsigned* __restrict__ m, int* __restrict__ flag) {
  const int l = (int)threadIdx.x;  // 64 threads
  unsigned acc = 0;
#pragma unroll
  for (int i = 0; i < 4; ++i) acc |= m[l * 4 + i];
  unsigned long long any = __ballot(acc & 0xFFFFFF00u);
  if (l == 0) *flag = any ? 1 : 0;
}

// ---- bitpack mask -> 1 bit/elem, u32 word = 32 cols ----
__global__ void pack_mask_kernel(const void* __restrict__ Mg, const int* __restrict__ flagp,
                                 unsigned* __restrict__ Wp) {
  const size_t i = (size_t)blockIdx.x * 256 + threadIdx.x;  // 2,097,152 words
  unsigned wbits = 0;
  if (*flagp) {
    const uint4* p = (const uint4*)((const unsigned char*)Mg + i * 32);
    uint4 a = p[0], b = p[1];
    unsigned v[8] = {a.x, a.y, a.z, a.w, b.x, b.y, b.z, b.w};
#pragma unroll
    for (int k = 0; k < 8; ++k)
#pragma unroll
      for (int bb = 0; bb < 4; ++bb)
        wbits |= (((v[k] >> (8 * bb)) & 0xFFu) ? 1u : 0u) << (4 * k + bb);
  } else {
    const uint4* p = (const uint4*)((const int*)Mg + i * 32);
#pragma unroll
    for (int k = 0; k < 8; ++k) {
      uint4 a = p[k];
      wbits |= (a.x ? 1u : 0u) << (4 * k)     | (a.y ? 1u : 0u) << (4 * k + 1) |
               (a.z ? 1u : 0u) << (4 * k + 2) | (a.w ? 1u : 0u) << (4 * k + 3);
    }
  }
  Wp[i] = wbits;
}

// ---- fp32 -> bf16 hi/lo planes (Q, K) ----
__global__ void conv_hilo_kernel(const float* __restrict__ X,
                                 unsigned short* __restrict__ Hh,
                                 unsigned short* __restrict__ Hl) {
  const size_t i = (size_t)blockIdx.x * 256 + threadIdx.x;
  float x[8];
  *(floatx4*)x       = *(const floatx4*)(X + i * 8);
  *(floatx4*)(x + 4) = *(const floatx4*)(X + i * 8 + 4);
  bf16x8 hv, lv;
  hilo8(x, hv, lv);
  *(bf16x8*)(Hh + i * 8) = hv;
  *(bf16x8*)(Hl + i * 8) = lv;
}

// ---- V (LK,DV) -> transposed bf16 hi/lo planes [DV][LK] ----
__global__ void conv_vt_kernel(const float* __restrict__ V,
                               unsigned short* __restrict__ Th,
                               unsigned short* __restrict__ Tl) {
  const int i = (int)(blockIdx.x * 256 + threadIdx.x);  // 131,072
  const int d = i >> 11, k = i & 2047;
  float x = V[(size_t)k * D_ + d];
  unsigned short hb = f2bf(x);
  float rem = x - bf2f(hb);
  Th[(size_t)d * LK_ + k] = hb;
  Tl[(size_t)d * LK_ + k] = (unsigned short)(__builtin_bit_cast(unsigned, rem) >> 16);
}

// ================= fused attention, swapped-QK, 16-wave k-split =================
template <bool PRE>
__global__ __launch_bounds__(1024, 4)
void attn_v5_kernel(const float* __restrict__ Qg, const float* __restrict__ Kg,
                    const float* __restrict__ Vg, const void* __restrict__ Mg,
                    const int* __restrict__ flagp, const unsigned* __restrict__ Wp,
                    const unsigned short* __restrict__ Qhp, const unsigned short* __restrict__ Qlp,
                    const unsigned short* __restrict__ Khp, const unsigned short* __restrict__ Klp,
                    const unsigned short* __restrict__ Vthp, const unsigned short* __restrict__ Vtlp,
                    float* __restrict__ Og, float* __restrict__ Ag) {
  const int tid = (int)threadIdx.x;
  const int l = tid & 63, w = tid >> 6, lm = l & 15, lg = l >> 4;
  const int hd = (int)blockIdx.y;
  const int q0 = (int)blockIdx.x * QB_;
  const int k0 = w * COLSW_;

  __shared__ __align__(16) float OM[8][QB_ * D_];   // 32 KB merge buffer
  __shared__ float SmM[NWAVE_][QB_];
  __shared__ float SmS[NWAVE_][QB_];

  const int mB = PRE ? 0 : *flagp;
  const unsigned char* Mb = (const unsigned char*)Mg;
  const int* Mi = (const int*)Mg;
  const size_t qrow = (size_t)hd * LQ_ + q0 + lm;   // this lane's q-row (global)

  // ---- Q B-fragments: Q[q0+lm][d = s*32 + lg*8 + jj], hi/lo ----
  bf16x8 qh[2], ql[2];
  if constexpr (PRE) {
    const unsigned short* qp  = Qhp + qrow * D_;
    const unsigned short* qp2 = Qlp + qrow * D_;
    qh[0] = *(const bf16x8*)(qp  + lg * 8); qh[1] = *(const bf16x8*)(qp  + 32 + lg * 8);
    ql[0] = *(const bf16x8*)(qp2 + lg * 8); ql[1] = *(const bf16x8*)(qp2 + 32 + lg * 8);
  } else {
    const float* qp = Qg + qrow * D_;
#pragma unroll
    for (int s = 0; s < 2; ++s) {
      float x[8];
      *(floatx4*)x       = *(const floatx4*)(qp + s * 32 + lg * 8);
      *(floatx4*)(x + 4) = *(const floatx4*)(qp + s * 32 + lg * 8 + 4);
      hilo8(x, qh[s], ql[s]);
    }
  }

  // ---- prefetch this lane's 4 packed-mask words (row lm, cols k0..k0+127) ----
  unsigned wmv[4];
  if constexpr (PRE) {
#pragma unroll
    for (int i = 0; i < 4; ++i) wmv[i] = Wp[qrow * (LK_ / 32) + w * 4 + i];
  }

  // =================== QK^T (swapped: S^T = K·Q^T) ===================
  // score (t,j): qrow = q0+lm, kcol = k0 + t*16 + lg*4 + j
  float sc[NT_][4];
#pragma unroll
  for (int t = 0; t < NT_; ++t) {
    bf16x8 kh[2], kl[2];
    const size_t krow = (size_t)hd * LK_ + k0 + t * 16 + lm;
    if constexpr (PRE) {
      const unsigned short* kp  = Khp + krow * D_;
      const unsigned short* kp2 = Klp + krow * D_;
      kh[0] = *(const bf16x8*)(kp  + lg * 8); kh[1] = *(const bf16x8*)(kp  + 32 + lg * 8);
      kl[0] = *(const bf16x8*)(kp2 + lg * 8); kl[1] = *(const bf16x8*)(kp2 + 32 + lg * 8);
    } else {
      const float* kp = Kg + krow * D_;
#pragma unroll
      for (int s = 0; s < 2; ++s) {
        float x[8];
        *(floatx4*)x       = *(const floatx4*)(kp + s * 32 + lg * 8);
        *(floatx4*)(x + 4) = *(const floatx4*)(kp + s * 32 + lg * 8 + 4);
        hilo8(x, kh[s], kl[s]);
      }
    }
    floatx4 acc = {0.f, 0.f, 0.f, 0.f};
#pragma unroll
    for (int s = 0; s < 2; ++s) {
      acc = mfma32(kh[s], qh[s], acc);
      acc = mfma32(kl[s], qh[s], acc);
      acc = mfma32(kh[s], ql[s], acc);
    }
    if constexpr (PRE) {
#pragma unroll
      for (int j = 0; j < 4; ++j) {
        const int mk = (int)((wmv[t >> 1] >> ((t & 1) * 16 + lg * 4 + j)) & 1u);
        sc[t][j] = mk ? -1e30f : acc[j] * 0.125f;
      }
    } else if (mB) {
      const unsigned mw = *(const unsigned*)(Mb + qrow * LK_ + k0 + t * 16 + lg * 4);
#pragma unroll
      for (int j = 0; j < 4; ++j)
        sc[t][j] = ((mw >> (8 * j)) & 0xFFu) ? -1e30f : acc[j] * 0.125f;
    } else {
      const uint4 mv = *(const uint4*)(Mi + qrow * LK_ + k0 + t * 16 + lg * 4);
      const unsigned mm[4] = {mv.x, mv.y, mv.z, mv.w};
#pragma unroll
      for (int j = 0; j < 4; ++j) sc[t][j] = mm[j] ? -1e30f : acc[j] * 0.125f;
    }
  }

  // =================== softmax (per-lane scalar stats; lg + wave merge) ===================
  float m = -1e30f;
#pragma unroll
  for (int t = 0; t < NT_; ++t)
#pragma unroll
    for (int j = 0; j < 4; ++j) m = fmaxf(m, sc[t][j]);
  m = fmaxf(m, __shfl_xor(m, 16, 64));
  m = fmaxf(m, __shfl_xor(m, 32, 64));
  if (lg == 0) SmM[w][lm] = m;
  __syncthreads();
  float mfin = SmM[0][lm];
#pragma unroll
  for (int ww = 1; ww < NWAVE_; ++ww) mfin = fmaxf(mfin, SmM[ww][lm]);

  float sum = 0.f;
#pragma unroll
  for (int t = 0; t < NT_; ++t)
#pragma unroll
    for (int j = 0; j < 4; ++j) {
      const float p = __expf(sc[t][j] - mfin);
      sc[t][j] = p;
      sum += p;
    }
  sum += __shfl_xor(sum, 16, 64);
  sum += __shfl_xor(sum, 32, 64);
  if (lg == 0) SmS[w][lm] = sum;
  __syncthreads();
  float tot = 0.f;
#pragma unroll
  for (int ww = 0; ww < NWAVE_; ++ww) tot += SmS[ww][lm];
  const float inv = 1.0f / tot;

  // =================== attn store + PV (K=16 MFMA, P already in A-layout) ===================
  floatx4 oacc[4];
#pragma unroll
  for (int n = 0; n < 4; ++n) oacc[n] = {0.f, 0.f, 0.f, 0.f};

#pragma unroll
  for (int t = 0; t < NT_; ++t) {
    float p[4];
#pragma unroll
    for (int j = 0; j < 4; ++j) p[j] = sc[t][j] * inv;
    // coalesced f32 attn store: row lm, 4 consecutive cols (16B/lane, 64B runs per row)
    floatx4 pv = {p[0], p[1], p[2], p[3]};
    *(floatx4*)(Ag + qrow * LK_ + k0 + t * 16 + lg * 4) = pv;

    short4v ph, pl;
    hilo4(p, ph, pl);
#pragma unroll
    for (int n = 0; n < 4; ++n) {
      short4v vh, vl;
      if constexpr (PRE) {
        const size_t vo = (size_t)(n * 16 + lm) * LK_ + k0 + t * 16 + lg * 4;
        vh = *(const short4v*)(Vthp + vo);
        vl = *(const short4v*)(Vtlp + vo);
      } else {
        float vx[4];
#pragma unroll
        for (int j = 0; j < 4; ++j)
          vx[j] = Vg[(size_t)(k0 + t * 16 + lg * 4 + j) * D_ + n * 16 + lm];
        hilo4(vx, vh, vl);
      }
      floatx4 o = oacc[n];
      o = mfma16(ph, vh, o);
      o = mfma16(pl, vh, o);
      o = mfma16(ph, vl, o);
      oacc[n] = o;
    }
  }

  // =================== 16-way k-split O merge (oacc[n][j] = O[lg*4+j][n*16+lm]) ===================
  __syncthreads();   // SmM/SmS reads done
  if (w >= 8) {
#pragma unroll
    for (int n = 0; n < 4; ++n)
#pragma unroll
      for (int j = 0; j < 4; ++j)
        OM[w - 8][(lg * 4 + j) * D_ + n * 16 + lm] = oacc[n][j];
  }
  __syncthreads();
  if (w < 8) {
#pragma unroll
    for (int n = 0; n < 4; ++n)
#pragma unroll
      for (int j = 0; j < 4; ++j) {
        const int idx = (lg * 4 + j) * D_ + n * 16 + lm;
        OM[w][idx] += oacc[n][j];
      }
  }
  __syncthreads();
  {
    const int i = tid;  // 1024 threads == QB_*D_ outputs
    float o = 0.f;
#pragma unroll
    for (int s = 0; s < 8; ++s) o += OM[s][i];
    Og[((size_t)hd * LQ_ + q0 + (i >> 6)) * D_ + (i & 63)] = o;
  }
}

extern "C" void kernel_launch(void* const* d_in, const int* in_sizes, int n_in,
                              void* d_out, int out_size, void* d_ws, size_t ws_size,
                              hipStream_t stream) {
  const float* Qg = (const float*)d_in[0];
  const float* Kg = (const float*)d_in[1];
  const float* Vg = (const float*)d_in[2];
  const void*  Mg = d_in[3];

  char* ws = (char*)d_ws;
  int* flag = (int*)ws;
  unsigned*       Wp  = (unsigned*)(ws + 16);
  unsigned short* Qhp = (unsigned short*)(ws + 16 + 8388608);
  unsigned short* Qlp = (unsigned short*)(ws + 16 + 8388608 + 4194304);
  unsigned short* Khp = (unsigned short*)(ws + 16 + 8388608 + 2 * 4194304);
  unsigned short* Klp = (unsigned short*)(ws + 16 + 8388608 + 3 * 4194304);
  unsigned short* Vth = (unsigned short*)(ws + 16 + 8388608 + 4 * 4194304);
  unsigned short* Vtl = (unsigned short*)(ws + 16 + 8388608 + 4 * 4194304 + 262144);
  const size_t WS_NEEDED = 16 + 8388608 + 4 * (size_t)4194304 + 2 * (size_t)262144;

  float* Og = (float*)d_out;                                // (H, LQ, DV)
  float* Ag = (float*)d_out + (size_t)H_ * LQ_ * D_;        // (H, LQ, LK)

  hipLaunchKernelGGL(detect_mask_kernel, dim3(1), dim3(64), 0, stream,
                     (const unsigned*)Mg, flag);

  dim3 grid(LQ_ / QB_, H_);
  if (ws_size >= WS_NEEDED) {
    hipLaunchKernelGGL(pack_mask_kernel, dim3(8192), dim3(256), 0, stream, Mg, flag, Wp);
    hipLaunchKernelGGL(conv_hilo_kernel, dim3(1024), dim3(256), 0, stream, Qg, Qhp, Qlp);
    hipLaunchKernelGGL(conv_hilo_kernel, dim3(1024), dim3(256), 0, stream, Kg, Khp, Klp);
    hipLaunchKernelGGL(conv_vt_kernel, dim3(512), dim3(256), 0, stream, Vg, Vth, Vtl);
    hipLaunchKernelGGL((attn_v5_kernel<true>), grid, dim3(1024), 0, stream,
                       Qg, Kg, Vg, Mg, flag, Wp, Qhp, Qlp, Khp, Klp, Vth, Vtl, Og, Ag);
  } else {
    hipLaunchKernelGGL((attn_v5_kernel<false>), grid, dim3(1024), 0, stream,
                       Qg, Kg, Vg, Mg, flag, Wp, Qhp, Qlp, Khp, Klp, Vth, Vtl, Og, Ag);
  }
}

// Round 8
// 735.048 us; speedup vs baseline: 1.1334x; 1.1334x over previous
//
#include <hip/hip_runtime.h>
#include <hip/hip_bf16.h>
#include <math.h>

#define H_ 16
#define LQ_ 2048
#define LK_ 2048
#define D_ 64
#define QB_ 16                  // q rows per block
#define NW_ 8                   // 512 threads, 8 waves
#define COLSW_ 256              // k-cols per wave (8-way k-split)
#define NT_ 16                  // 16-col tiles per wave

using bf16x8  = __attribute__((ext_vector_type(8))) short;
using short4v = __attribute__((ext_vector_type(4))) short;
using floatx4 = __attribute__((ext_vector_type(4))) float;

__device__ __forceinline__ unsigned short f2bf(float x) {
  unsigned u = __builtin_bit_cast(unsigned, x);
  return (unsigned short)((u + 0x7fffu + ((u >> 16) & 1u)) >> 16);
}
__device__ __forceinline__ float bf2f(unsigned short b) {
  return __builtin_bit_cast(float, ((unsigned)b) << 16);
}
__device__ __forceinline__ void hilo8(const float* __restrict__ x, bf16x8& hv, bf16x8& lv) {
#pragma unroll
  for (int j = 0; j < 8; ++j) {
    unsigned short hb = f2bf(x[j]);
    float d = x[j] - bf2f(hb);
    hv[j] = (short)hb;
    lv[j] = (short)(unsigned short)(__builtin_bit_cast(unsigned, d) >> 16);
  }
}
__device__ __forceinline__ void hilo4(const float* __restrict__ x, short4v& hv, short4v& lv) {
#pragma unroll
  for (int j = 0; j < 4; ++j) {
    unsigned short hb = f2bf(x[j]);
    float d = x[j] - bf2f(hb);
    hv[j] = (short)hb;
    lv[j] = (short)(unsigned short)(__builtin_bit_cast(unsigned, d) >> 16);
  }
}

__device__ __forceinline__ floatx4 mfma32(bf16x8 a, bf16x8 b, floatx4 c) {
  return __builtin_amdgcn_mfma_f32_16x16x32_bf16(a, b, c, 0, 0, 0);
}
__device__ __forceinline__ floatx4 mfma16(short4v a, short4v b, floatx4 c) {
#if __has_builtin(__builtin_amdgcn_mfma_f32_16x16x16bf16_1k)
  return __builtin_amdgcn_mfma_f32_16x16x16bf16_1k(a, b, c, 0, 0, 0);
#else
  floatx4 d;
  asm("v_mfma_f32_16x16x16_bf16 %0, %1, %2, %3" : "=&v"(d) : "v"(a), "v"(b), "v"(c));
  return d;
#endif
}

// ---- mask dtype detect: int32 0/1 words never have nonzero high bytes ----
__global__ void detect_mask_kernel(const unsigned* __restrict__ m, int* __restrict__ flag) {
  const int l = (int)threadIdx.x;  // 64 threads
  unsigned acc = 0;
#pragma unroll
  for (int i = 0; i < 4; ++i) acc |= m[l * 4 + i];
  unsigned long long any = __ballot(acc & 0xFFFFFF00u);
  if (l == 0) *flag = any ? 1 : 0;
}

// ---- bitpack mask -> 1 bit/elem, u32 word = 32 cols ----
__global__ void pack_mask_kernel(const void* __restrict__ Mg, const int* __restrict__ flagp,
                                 unsigned* __restrict__ Wp) {
  const size_t i = (size_t)blockIdx.x * 256 + threadIdx.x;  // 2,097,152 words
  unsigned wbits = 0;
  if (*flagp) {
    const uint4* p = (const uint4*)((const unsigned char*)Mg + i * 32);
    uint4 a = p[0], b = p[1];
    unsigned v[8] = {a.x, a.y, a.z, a.w, b.x, b.y, b.z, b.w};
#pragma unroll
    for (int k = 0; k < 8; ++k)
#pragma unroll
      for (int bb = 0; bb < 4; ++bb)
        wbits |= (((v[k] >> (8 * bb)) & 0xFFu) ? 1u : 0u) << (4 * k + bb);
  } else {
    const uint4* p = (const uint4*)((const int*)Mg + i * 32);
#pragma unroll
    for (int k = 0; k < 8; ++k) {
      uint4 a = p[k];
      wbits |= (a.x ? 1u : 0u) << (4 * k)     | (a.y ? 1u : 0u) << (4 * k + 1) |
               (a.z ? 1u : 0u) << (4 * k + 2) | (a.w ? 1u : 0u) << (4 * k + 3);
    }
  }
  Wp[i] = wbits;
}

// ---- fp32 -> bf16 hi/lo planes (Q pre-scaled by 0.125, K by 1.0) ----
__global__ void conv_hilo_kernel(const float* __restrict__ X,
                                 unsigned short* __restrict__ Hh,
                                 unsigned short* __restrict__ Hl, float scale) {
  const size_t i = (size_t)blockIdx.x * 256 + threadIdx.x;
  float x[8];
  *(floatx4*)x       = *(const floatx4*)(X + i * 8);
  *(floatx4*)(x + 4) = *(const floatx4*)(X + i * 8 + 4);
#pragma unroll
  for (int j = 0; j < 8; ++j) x[j] *= scale;
  bf16x8 hv, lv;
  hilo8(x, hv, lv);
  *(bf16x8*)(Hh + i * 8) = hv;
  *(bf16x8*)(Hl + i * 8) = lv;
}

// ---- V (LK,DV) -> transposed packed u32 plane [DV][LK]: word = hi | (lo<<16) ----
__global__ void conv_vc_kernel(const float* __restrict__ V, unsigned* __restrict__ Vc) {
  const int i = (int)(blockIdx.x * 256 + threadIdx.x);  // 131,072
  const int d = i >> 11, k = i & 2047;
  float x = V[(size_t)k * D_ + d];
  unsigned short hb = f2bf(x);
  float rem = x - bf2f(hb);
  unsigned short lb = (unsigned short)(__builtin_bit_cast(unsigned, rem) >> 16);
  Vc[(size_t)d * LK_ + k] = (unsigned)hb | ((unsigned)lb << 16);
}

// ================= fused attention: swapped-QK, 8-wave k-split, no-spill =================
template <bool PRE>
__global__ __launch_bounds__(512, 2)
void attn_v7_kernel(const float* __restrict__ Qg, const float* __restrict__ Kg,
                    const float* __restrict__ Vg, const void* __restrict__ Mg,
                    const int* __restrict__ flagp, const unsigned* __restrict__ Wp,
                    const unsigned short* __restrict__ Qhp, const unsigned short* __restrict__ Qlp,
                    const unsigned short* __restrict__ Khp, const unsigned short* __restrict__ Klp,
                    const unsigned* __restrict__ Vcp,
                    float* __restrict__ Og, float* __restrict__ Ag) {
  const int tid = (int)threadIdx.x;
  const int l = tid & 63, w = tid >> 6, lm = l & 15, lg = l >> 4;
  const int hd = (int)blockIdx.y;
  const int q0 = (int)blockIdx.x * QB_;
  const int k0 = w * COLSW_;

  __shared__ __align__(16) float OM[4][QB_ * D_];   // 16 KB merge buffer
  __shared__ float SmM[NW_][QB_];
  __shared__ float SmS[NW_][QB_];

  const int mB = PRE ? 0 : *flagp;
  const unsigned char* Mb = (const unsigned char*)Mg;
  const int* Mi = (const int*)Mg;
  const size_t qrow = (size_t)hd * LQ_ + q0 + lm;   // this lane's q-row (global)

  // ---- Q B-fragments (pre-scaled by 0.125 in PRE planes) ----
  bf16x8 qh[2], ql[2];
  if constexpr (PRE) {
    const unsigned short* qp  = Qhp + qrow * D_;
    const unsigned short* qp2 = Qlp + qrow * D_;
    qh[0] = *(const bf16x8*)(qp  + lg * 8); qh[1] = *(const bf16x8*)(qp  + 32 + lg * 8);
    ql[0] = *(const bf16x8*)(qp2 + lg * 8); ql[1] = *(const bf16x8*)(qp2 + 32 + lg * 8);
  } else {
    const float* qp = Qg + qrow * D_;
#pragma unroll
    for (int s = 0; s < 2; ++s) {
      float x[8];
      *(floatx4*)x       = *(const floatx4*)(qp + s * 32 + lg * 8);
      *(floatx4*)(x + 4) = *(const floatx4*)(qp + s * 32 + lg * 8 + 4);
      hilo8(x, qh[s], ql[s]);
    }
  }

  // ---- prefetch this lane's 8 packed-mask words (row lm, cols k0..k0+255) ----
  unsigned wmv[8];
  if constexpr (PRE) {
#pragma unroll
    for (int i = 0; i < 8; ++i) wmv[i] = Wp[qrow * (LK_ / 32) + w * 8 + i];
  }

  // =================== QK^T (swapped: S^T = K·Q^T), t-pair batched ===================
  // score (t,j): qrow = q0+lm, kcol = k0 + t*16 + lg*4 + j
  float sc[NT_][4];
#pragma unroll
  for (int tp = 0; tp < NT_ / 2; ++tp) {
    const int t0 = 2 * tp, t1 = 2 * tp + 1;
    bf16x8 khA[2], klA[2], khB[2], klB[2];
    const size_t krowA = (size_t)hd * LK_ + k0 + t0 * 16 + lm;
    const size_t krowB = (size_t)hd * LK_ + k0 + t1 * 16 + lm;
    if constexpr (PRE) {
      const unsigned short* kpA  = Khp + krowA * D_;
      const unsigned short* kpA2 = Klp + krowA * D_;
      const unsigned short* kpB  = Khp + krowB * D_;
      const unsigned short* kpB2 = Klp + krowB * D_;
      khA[0] = *(const bf16x8*)(kpA  + lg * 8); khA[1] = *(const bf16x8*)(kpA  + 32 + lg * 8);
      klA[0] = *(const bf16x8*)(kpA2 + lg * 8); klA[1] = *(const bf16x8*)(kpA2 + 32 + lg * 8);
      khB[0] = *(const bf16x8*)(kpB  + lg * 8); khB[1] = *(const bf16x8*)(kpB  + 32 + lg * 8);
      klB[0] = *(const bf16x8*)(kpB2 + lg * 8); klB[1] = *(const bf16x8*)(kpB2 + 32 + lg * 8);
    } else {
      const float* kpA = Kg + krowA * D_;
      const float* kpB = Kg + krowB * D_;
#pragma unroll
      for (int s = 0; s < 2; ++s) {
        float xa[8], xb[8];
        *(floatx4*)xa       = *(const floatx4*)(kpA + s * 32 + lg * 8);
        *(floatx4*)(xa + 4) = *(const floatx4*)(kpA + s * 32 + lg * 8 + 4);
        *(floatx4*)xb       = *(const floatx4*)(kpB + s * 32 + lg * 8);
        *(floatx4*)(xb + 4) = *(const floatx4*)(kpB + s * 32 + lg * 8 + 4);
        hilo8(xa, khA[s], klA[s]);
        hilo8(xb, khB[s], klB[s]);
      }
    }
    floatx4 accA = {0.f, 0.f, 0.f, 0.f};
    floatx4 accB = {0.f, 0.f, 0.f, 0.f};
#pragma unroll
    for (int s = 0; s < 2; ++s) {
      accA = mfma32(khA[s], qh[s], accA);
      accB = mfma32(khB[s], qh[s], accB);
      accA = mfma32(klA[s], qh[s], accA);
      accB = mfma32(klB[s], qh[s], accB);
      accA = mfma32(khA[s], ql[s], accA);
      accB = mfma32(khB[s], ql[s], accB);
    }
    if constexpr (PRE) {
      const unsigned w0 = wmv[tp];  // word covers cols tp*32 .. tp*32+31 of this strip
#pragma unroll
      for (int j = 0; j < 4; ++j) {
        sc[t0][j] = ((w0 >> (lg * 4 + j)) & 1u)        ? -1e30f : accA[j];
        sc[t1][j] = ((w0 >> (16 + lg * 4 + j)) & 1u)   ? -1e30f : accB[j];
      }
    } else if (mB) {
      const unsigned mwA = *(const unsigned*)(Mb + qrow * LK_ + k0 + t0 * 16 + lg * 4);
      const unsigned mwB = *(const unsigned*)(Mb + qrow * LK_ + k0 + t1 * 16 + lg * 4);
#pragma unroll
      for (int j = 0; j < 4; ++j) {
        sc[t0][j] = ((mwA >> (8 * j)) & 0xFFu) ? -1e30f : accA[j] * 0.125f;
        sc[t1][j] = ((mwB >> (8 * j)) & 0xFFu) ? -1e30f : accB[j] * 0.125f;
      }
    } else {
      const uint4 mvA = *(const uint4*)(Mi + qrow * LK_ + k0 + t0 * 16 + lg * 4);
      const uint4 mvB = *(const uint4*)(Mi + qrow * LK_ + k0 + t1 * 16 + lg * 4);
      const unsigned ma[4] = {mvA.x, mvA.y, mvA.z, mvA.w};
      const unsigned mb2[4] = {mvB.x, mvB.y, mvB.z, mvB.w};
#pragma unroll
      for (int j = 0; j < 4; ++j) {
        sc[t0][j] = ma[j]  ? -1e30f : accA[j] * 0.125f;
        sc[t1][j] = mb2[j] ? -1e30f : accB[j] * 0.125f;
      }
    }
  }

  // =================== softmax (per-lane scalar stats; lg + wave merge) ===================
  float m = -1e30f;
#pragma unroll
  for (int t = 0; t < NT_; ++t)
#pragma unroll
    for (int j = 0; j < 4; ++j) m = fmaxf(m, sc[t][j]);
  m = fmaxf(m, __shfl_xor(m, 16, 64));
  m = fmaxf(m, __shfl_xor(m, 32, 64));
  if (lg == 0) SmM[w][lm] = m;
  __syncthreads();
  float mfin = SmM[0][lm];
#pragma unroll
  for (int ww = 1; ww < NW_; ++ww) mfin = fmaxf(mfin, SmM[ww][lm]);

  float sum = 0.f;
#pragma unroll
  for (int t = 0; t < NT_; ++t)
#pragma unroll
    for (int j = 0; j < 4; ++j) {
      const float p = __expf(sc[t][j] - mfin);
      sc[t][j] = p;
      sum += p;
    }
  sum += __shfl_xor(sum, 16, 64);
  sum += __shfl_xor(sum, 32, 64);
  if (lg == 0) SmS[w][lm] = sum;
  __syncthreads();
  float tot = 0.f;
#pragma unroll
  for (int ww = 0; ww < NW_; ++ww) tot += SmS[ww][lm];
  const float inv = 1.0f / tot;

  // =================== attn store + PV (K=16 MFMA, P already in A-layout) ===================
  floatx4 oacc[4];
#pragma unroll
  for (int n = 0; n < 4; ++n) oacc[n] = {0.f, 0.f, 0.f, 0.f};

#pragma unroll
  for (int t = 0; t < NT_; ++t) {
    float p[4];
#pragma unroll
    for (int j = 0; j < 4; ++j) p[j] = sc[t][j] * inv;
    // coalesced f32 attn store: row lm, 4 consecutive cols (16B/lane, 64B runs per row)
    floatx4 pv = {p[0], p[1], p[2], p[3]};
    *(floatx4*)(Ag + qrow * LK_ + k0 + t * 16 + lg * 4) = pv;

    short4v ph, pl;
    hilo4(p, ph, pl);

    if constexpr (PRE) {
      // batched packed-V loads first (4 x 16B), then 12 MFMAs
      uint4 vw[4];
#pragma unroll
      for (int n = 0; n < 4; ++n)
        vw[n] = *(const uint4*)(Vcp + (size_t)(n * 16 + lm) * LK_ + k0 + t * 16 + lg * 4);
#pragma unroll
      for (int n = 0; n < 4; ++n) {
        short4v vh, vl;
        const unsigned vv[4] = {vw[n].x, vw[n].y, vw[n].z, vw[n].w};
#pragma unroll
        for (int j = 0; j < 4; ++j) {
          vh[j] = (short)(unsigned short)(vv[j] & 0xFFFFu);
          vl[j] = (short)(unsigned short)(vv[j] >> 16);
        }
        floatx4 o = oacc[n];
        o = mfma16(ph, vh, o);
        o = mfma16(pl, vh, o);
        o = mfma16(ph, vl, o);
        oacc[n] = o;
      }
    } else {
#pragma unroll
      for (int n = 0; n < 4; ++n) {
        float vx[4];
#pragma unroll
        for (int j = 0; j < 4; ++j)
          vx[j] = Vg[(size_t)(k0 + t * 16 + lg * 4 + j) * D_ + n * 16 + lm];
        short4v vh, vl;
        hilo4(vx, vh, vl);
        floatx4 o = oacc[n];
        o = mfma16(ph, vh, o);
        o = mfma16(pl, vh, o);
        o = mfma16(ph, vl, o);
        oacc[n] = o;
      }
    }
  }

  // =================== 8-way k-split O merge (oacc[n][j] = O[lg*4+j][n*16+lm]) ===================
  __syncthreads();   // SmM/SmS reads done
  if (w >= 4) {
#pragma unroll
    for (int n = 0; n < 4; ++n)
#pragma unroll
      for (int j = 0; j < 4; ++j)
        OM[w - 4][(lg * 4 + j) * D_ + n * 16 + lm] = oacc[n][j];
  }
  __syncthreads();
  if (w < 4) {
#pragma unroll
    for (int n = 0; n < 4; ++n)
#pragma unroll
      for (int j = 0; j < 4; ++j) {
        const int idx = (lg * 4 + j) * D_ + n * 16 + lm;
        OM[w][idx] += oacc[n][j];
      }
  }
  __syncthreads();
#pragma unroll
  for (int i = tid; i < QB_ * D_; i += 512) {
    const float o = OM[0][i] + OM[1][i] + OM[2][i] + OM[3][i];
    Og[((size_t)hd * LQ_ + q0 + (i >> 6)) * D_ + (i & 63)] = o;
  }
}

extern "C" void kernel_launch(void* const* d_in, const int* in_sizes, int n_in,
                              void* d_out, int out_size, void* d_ws, size_t ws_size,
                              hipStream_t stream) {
  const float* Qg = (const float*)d_in[0];
  const float* Kg = (const float*)d_in[1];
  const float* Vg = (const float*)d_in[2];
  const void*  Mg = d_in[3];

  char* ws = (char*)d_ws;
  int* flag = (int*)ws;
  unsigned*       Wp  = (unsigned*)(ws + 16);
  unsigned short* Qhp = (unsigned short*)(ws + 16 + 8388608);
  unsigned short* Qlp = (unsigned short*)(ws + 16 + 8388608 + 4194304);
  unsigned short* Khp = (unsigned short*)(ws + 16 + 8388608 + 2 * 4194304);
  unsigned short* Klp = (unsigned short*)(ws + 16 + 8388608 + 3 * 4194304);
  unsigned*       Vcp = (unsigned*)(ws + 16 + 8388608 + 4 * 4194304);
  const size_t WS_NEEDED = 16 + 8388608 + 4 * (size_t)4194304 + (size_t)524288;

  float* Og = (float*)d_out;                                // (H, LQ, DV)
  float* Ag = (float*)d_out + (size_t)H_ * LQ_ * D_;        // (H, LQ, LK)

  hipLaunchKernelGGL(detect_mask_kernel, dim3(1), dim3(64), 0, stream,
                     (const unsigned*)Mg, flag);

  dim3 grid(LQ_ / QB_, H_);
  if (ws_size >= WS_NEEDED) {
    hipLaunchKernelGGL(pack_mask_kernel, dim3(8192), dim3(256), 0, stream, Mg, flag, Wp);
    hipLaunchKernelGGL(conv_hilo_kernel, dim3(1024), dim3(256), 0, stream, Qg, Qhp, Qlp, 0.125f);
    hipLaunchKernelGGL(conv_hilo_kernel, dim3(1024), dim3(256), 0, stream, Kg, Khp, Klp, 1.0f);
    hipLaunchKernelGGL(conv_vc_kernel, dim3(512), dim3(256), 0, stream, Vg, Vcp);
    hipLaunchKernelGGL((attn_v7_kernel<true>), grid, dim3(512), 0, stream,
                       Qg, Kg, Vg, Mg, flag, Wp, Qhp, Qlp, Khp, Klp, Vcp, Og, Ag);
  } else {
    hipLaunchKernelGGL((attn_v7_kernel<false>), grid, dim3(512), 0, stream,
                       Qg, Kg, Vg, Mg, flag, Wp, Qhp, Qlp, Khp, Klp, Vcp, Og, Ag);
  }
}